// Round 4
// baseline (554.243 us; speedup 1.0000x reference)
//
#include <hip/hip_runtime.h>
#include <math.h>

#define L_LEVELS 16
#define T_SIZE   16384
#define BS_N     524288
#define TPB      1024
#define PPB      2048                 // points per block (2 per thread)
#define NBLOCKS  (BS_N / PPB)         // 256 = one per CU

typedef float v2f __attribute__((ext_vector_type(2)));

struct Scales { float s[L_LEVELS]; };

// hash primes mod 2^14 (only low 14 bits of the int64 hash survive % T)
#define P2_14 ((unsigned)(2654435761u & (T_SIZE - 1)))
#define P3_14 ((unsigned)(805459861u  & (T_SIZE - 1)))
#define MASK3 ((T_SIZE - 1) << 3)     // byte-offset mask (8B entries)

#define RPN 257                       // padded repack stride (v2f units)

__device__ __forceinline__ void level_point(const v2f* __restrict__ tab,
                                            float scale,
                                            float px, float py, float pz,
                                            v2f& acc)
{
    float sx = px * scale, sy = py * scale, sz = pz * scale;
    float fx = floorf(sx), fy = floorf(sy), fz = floorf(sz);
    float cx = ceilf(sx),  cy = ceilf(sy),  cz = ceilf(sz);

    unsigned ix0 = (unsigned)(int)fx, ix1 = (unsigned)(int)cx;
    unsigned iy0 = (unsigned)(int)fy, iy1 = (unsigned)(int)cy;
    unsigned iz0 = (unsigned)(int)fz, iz1 = (unsigned)(int)cz;
    unsigned hy0 = (iy0 & 0xFFFFFFu) * P2_14;
    unsigned hy1 = (iy1 & 0xFFFFFFu) * P2_14;
    unsigned hz0 = ((iz0 & 0xFFFFFFu) * P3_14) << 3;
    unsigned hz1 = ((iz1 & 0xFFFFFFu) * P3_14) << 3;
    unsigned a00 = (ix0 ^ hy0) << 3, a01 = (ix0 ^ hy1) << 3;
    unsigned a10 = (ix1 ^ hy0) << 3, a11 = (ix1 ^ hy1) << 3;

    v2f ex = (v2f){fx, cx} - px;
    v2f ey = (v2f){fy, cy} - py;
    v2f ez = (v2f){fz, cz} - pz;
    v2f qx = ex * ex, qy = ey * ey, qz = ez * ez;
    v2f AB0 = qx + qy.xx, AB1 = qx + qy.yy;
    v2f S00 = AB0 + qz.xx, S01 = AB0 + qz.yy;
    v2f S10 = AB1 + qz.xx, S11 = AB1 + qz.yy;

    float d0 = sqrtf(S00.x), d1 = sqrtf(S01.x);
    float d2 = sqrtf(S10.x), d3 = sqrtf(S11.x);
    float d4 = sqrtf(S00.y), d5 = sqrtf(S01.y);
    float d6 = sqrtf(S10.y), d7 = sqrtf(S11.y);

    const char* tb = (const char*)tab;
    v2f f0 = *(const v2f*)(tb + ((a00 ^ hz0) & MASK3));
    v2f f1 = *(const v2f*)(tb + ((a00 ^ hz1) & MASK3));
    v2f f2 = *(const v2f*)(tb + ((a01 ^ hz0) & MASK3));
    v2f f3 = *(const v2f*)(tb + ((a01 ^ hz1) & MASK3));
    v2f f4 = *(const v2f*)(tb + ((a10 ^ hz0) & MASK3));
    v2f f5 = *(const v2f*)(tb + ((a10 ^ hz1) & MASK3));
    v2f f6 = *(const v2f*)(tb + ((a11 ^ hz0) & MASK3));
    v2f f7 = *(const v2f*)(tb + ((a11 ^ hz1) & MASK3));

    acc += f0 * d0;  acc += f1 * d1;  acc += f2 * d2;  acc += f3 * d3;
    acc += f4 * d4;  acc += f5 * d5;  acc += f6 * d6;  acc += f7 * d7;
}

// Point-major fused kernel: block = 2048-point chunk, loops all 16 levels.
// Level table (128 KB) lives in LDS; next table is T14-staged (global->reg
// during compute, reg->LDS in the barrier window). Output repacked via a
// 16 KB LDS region so every store is a full 64B line, 1KB/wave-instr.
__global__ __launch_bounds__(TPB) void mrhe_kernel(
    const float* __restrict__ pts,
    const float* __restrict__ tables,
    float* __restrict__ out,
    Scales sc)
{
    __shared__ __align__(16) v2f tab[T_SIZE];   // 128 KB current level table
    __shared__ __align__(16) v2f rp[8][RPN];    // 16.06 KB repack (padded)

    const unsigned tid   = threadIdx.x;
    const unsigned pbase = blockIdx.x * PPB;

    // each thread owns points p0 = pbase+tid, p1 = pbase+1024+tid
    const float* pp0 = pts + (size_t)(pbase + tid) * 3;
    const float* pp1 = pts + (size_t)(pbase + 1024 + tid) * 3;
    float px0 = pp0[0], py0 = pp0[1], pz0 = pp0[2];
    float px1 = pp1[0], py1 = pp1[1], pz1 = pp1[2];

    // ---- prologue: stage table 0 direct-to-LDS; issue reg loads for table 1
    {
        const char* gsrc = (const char*)tables;   // level 0
        char* lbase = (char*)tab;
#pragma unroll
        for (int k = 0; k < 8; ++k) {
            unsigned off = (k * TPB + tid) * 16u;
            __builtin_amdgcn_global_load_lds(
                (const __attribute__((address_space(1))) unsigned int*)(gsrc + off),
                (__attribute__((address_space(3))) unsigned int*)(lbase + off),
                16, 0, 0);
        }
    }
    float4 R[8];   // staging regs for the NEXT level's table (128 B/thread)
    {
        const float4* s1 = (const float4*)(tables + (size_t)1 * T_SIZE * 2);
#pragma unroll
        for (int k = 0; k < 8; ++k) R[k] = s1[k * TPB + tid];
    }
    __syncthreads();   // drains vmcnt: table 0 in LDS (R also arrived)

    v2f acc0[8], acc1[8];
#pragma unroll
    for (int i = 0; i < 8; ++i) { acc0[i] = (v2f)0.f; acc1[i] = (v2f)0.f; }

    float4* __restrict__ out4 = (float4*)out;

#pragma unroll
    for (int l = 0; l < L_LEVELS; ++l) {
        const int lp = l & 7;
        const float scale = sc.s[l];   // constant index after unroll -> SGPR

        level_point(tab, scale, px0, py0, pz0, acc0[lp]);
        level_point(tab, scale, px1, py1, pz1, acc1[lp]);

        if (lp == 7) {
            // ---- repack super-phase (levels l-7..l) and store full lines ----
            const int sup = l >> 3;
#pragma unroll
            for (int s = 0; s < 8; ++s) {
                __syncthreads();   // rp free / previous sub-pass read done
                if (s < 4) {
                    if ((tid >> 8) == (unsigned)s) {
                        unsigned q = tid & 255u;
#pragma unroll
                        for (int lv = 0; lv < 8; ++lv) rp[lv][q] = acc0[lv];
                    }
                } else {
                    if ((tid >> 8) == (unsigned)(s - 4)) {
                        unsigned q = tid & 255u;
#pragma unroll
                        for (int lv = 0; lv < 8; ++lv) rp[lv][q] = acc1[lv];
                    }
                }
                __syncthreads();   // rp visible
                // every thread stores one 16B chunk: 1 KB contiguous per wave
                unsigned pq = tid >> 2, j = tid & 3u;   // point-in-256, chunk
                v2f lo = rp[2 * j][pq];
                v2f hi = rp[2 * j + 1][pq];
                float4 val = make_float4(lo.x, lo.y, hi.x, hi.y);
                size_t idx = (size_t)(pbase + s * 256 + pq) * 8 + sup * 4 + j;
                out4[idx] = val;
            }
            if (l == 7) {
#pragma unroll
                for (int i = 0; i < 8; ++i) { acc0[i] = (v2f)0.f; acc1[i] = (v2f)0.f; }
            }
        }

        if (l < L_LEVELS - 1) {
            __syncthreads();          // everyone done gathering table l
            // reg -> LDS: table l+1 (compiler inserts vmcnt wait on R)
#pragma unroll
            for (int k = 0; k < 8; ++k)
                ((float4*)tab)[k * TPB + tid] = R[k];
            if (l < L_LEVELS - 2) {   // issue loads for table l+2
                const float4* sn = (const float4*)(tables + (size_t)(l + 2) * T_SIZE * 2);
#pragma unroll
                for (int k = 0; k < 8; ++k) R[k] = sn[k * TPB + tid];
            }
            __syncthreads();          // table l+1 visible
        }
    }
}

extern "C" void kernel_launch(void* const* d_in, const int* in_sizes, int n_in,
                              void* d_out, int out_size, void* d_ws, size_t ws_size,
                              hipStream_t stream) {
    const float* pts    = (const float*)d_in[0];
    const float* tables = (const float*)d_in[1];
    float* out = (float*)d_out;

    // numpy-exact: growth in f64, levels = float32(16 * g**l)
    Scales sc;
    double g = exp((log(512.0) - log(16.0)) / 15.0);
    for (int l = 0; l < L_LEVELS; ++l) sc.s[l] = (float)(16.0 * pow(g, (double)l));

    dim3 grid(NBLOCKS);    // 256 blocks, 1 per CU
    dim3 block(TPB);
    hipLaunchKernelGGL(mrhe_kernel, grid, block, 0, stream, pts, tables, out, sc);
}

// Round 5
// 273.432 us; speedup vs baseline: 2.0270x; 2.0270x over previous
//
#include <hip/hip_runtime.h>
#include <math.h>

#define L_LEVELS 16
#define T_SIZE   16384
#define BS_N     524288
#define TPB      1024
#define PPB      2048                 // points per block (2 per thread)
#define NBLOCKS  (BS_N / PPB)         // 256 = one block per CU

typedef float v2f __attribute__((ext_vector_type(2)));

struct Scales { float s[L_LEVELS]; };

// hash primes mod 2^14 (only low 14 bits of the int64 hash survive % T)
#define P2_14 ((unsigned)(2654435761u & (T_SIZE - 1)))
#define P3_14 ((unsigned)(805459861u  & (T_SIZE - 1)))
#define MASK3 ((T_SIZE - 1) << 3)     // byte-offset mask (8B entries)

__device__ __forceinline__ void level_point(const v2f* __restrict__ tab,
                                            float scale,
                                            float px, float py, float pz,
                                            v2f& acc)
{
    float sx = px * scale, sy = py * scale, sz = pz * scale;
    float fx = floorf(sx), fy = floorf(sy), fz = floorf(sz);
    float cx = ceilf(sx),  cy = ceilf(sy),  cz = ceilf(sz);

    unsigned ix0 = (unsigned)(int)fx, ix1 = (unsigned)(int)cx;
    unsigned iy0 = (unsigned)(int)fy, iy1 = (unsigned)(int)cy;
    unsigned iz0 = (unsigned)(int)fz, iz1 = (unsigned)(int)cz;
    unsigned hy0 = (iy0 & 0xFFFFFFu) * P2_14;
    unsigned hy1 = (iy1 & 0xFFFFFFu) * P2_14;
    unsigned hz0 = ((iz0 & 0xFFFFFFu) * P3_14) << 3;
    unsigned hz1 = ((iz1 & 0xFFFFFFu) * P3_14) << 3;
    unsigned a00 = (ix0 ^ hy0) << 3, a01 = (ix0 ^ hy1) << 3;
    unsigned a10 = (ix1 ^ hy0) << 3, a11 = (ix1 ^ hy1) << 3;

    v2f ex = (v2f){fx, cx} - px;
    v2f ey = (v2f){fy, cy} - py;
    v2f ez = (v2f){fz, cz} - pz;
    v2f qx = ex * ex, qy = ey * ey, qz = ez * ez;
    v2f AB0 = qx + qy.xx, AB1 = qx + qy.yy;
    v2f S00 = AB0 + qz.xx, S01 = AB0 + qz.yy;
    v2f S10 = AB1 + qz.xx, S11 = AB1 + qz.yy;

    float d0 = sqrtf(S00.x), d1 = sqrtf(S01.x);
    float d2 = sqrtf(S10.x), d3 = sqrtf(S11.x);
    float d4 = sqrtf(S00.y), d5 = sqrtf(S01.y);
    float d6 = sqrtf(S10.y), d7 = sqrtf(S11.y);

    const char* tb = (const char*)tab;
    v2f f0 = *(const v2f*)(tb + ((a00 ^ hz0) & MASK3));
    v2f f1 = *(const v2f*)(tb + ((a00 ^ hz1) & MASK3));
    v2f f2 = *(const v2f*)(tb + ((a01 ^ hz0) & MASK3));
    v2f f3 = *(const v2f*)(tb + ((a01 ^ hz1) & MASK3));
    v2f f4 = *(const v2f*)(tb + ((a10 ^ hz0) & MASK3));
    v2f f5 = *(const v2f*)(tb + ((a10 ^ hz1) & MASK3));
    v2f f6 = *(const v2f*)(tb + ((a11 ^ hz0) & MASK3));
    v2f f7 = *(const v2f*)(tb + ((a11 ^ hz1) & MASK3));

    acc += f0 * d0;  acc += f1 * d1;  acc += f2 * d2;  acc += f3 * d3;
    acc += f4 * d4;  acc += f5 * d5;  acc += f6 * d6;  acc += f7 * d7;
}

// Point-major fused kernel, no-spill edition.
// __launch_bounds__(1024, 4): 4 waves/EU == the 1 block/CU that 128 KB LDS
// forces anyway -> compiler VGPR cap 128 (not 64) -> acc[16]+R[8] stay in
// registers. Each thread stores its own 64-B output line directly (levels
// 8s..8s+7 of one point); the 4 dwordx4 stores complete the line within ns
// in one L2 -> exactly one writeback, no repack LDS, no extra barriers.
__global__ __launch_bounds__(TPB, 4) void mrhe_kernel(
    const float* __restrict__ pts,
    const float* __restrict__ tables,
    float* __restrict__ out,
    Scales sc)
{
    __shared__ __align__(16) v2f tab[T_SIZE];   // 128 KB current level table

    const unsigned tid   = threadIdx.x;
    const unsigned pbase = blockIdx.x * PPB;

    const float* pp0 = pts + (size_t)(pbase + tid) * 3;
    const float* pp1 = pts + (size_t)(pbase + TPB + tid) * 3;
    float px0 = pp0[0], py0 = pp0[1], pz0 = pp0[2];
    float px1 = pp1[0], py1 = pp1[1], pz1 = pp1[2];

    // ---- prologue: table 0 direct-to-LDS; reg loads for table 1 ----
    {
        const char* gsrc = (const char*)tables;
        char* lbase = (char*)tab;
#pragma unroll
        for (int k = 0; k < 8; ++k) {
            unsigned off = (k * TPB + tid) * 16u;
            __builtin_amdgcn_global_load_lds(
                (const __attribute__((address_space(1))) unsigned int*)(gsrc + off),
                (__attribute__((address_space(3))) unsigned int*)(lbase + off),
                16, 0, 0);
        }
    }
    float4 R[8];   // T14 staging regs for the NEXT level's table
    {
        const float4* s1 = (const float4*)(tables + (size_t)T_SIZE * 2);
#pragma unroll
        for (int k = 0; k < 8; ++k) R[k] = s1[k * TPB + tid];
    }
    __syncthreads();   // vmcnt drained: table 0 resident

    float4* __restrict__ out4 = (float4*)out;

#pragma unroll
    for (int sup = 0; sup < 2; ++sup) {
        v2f acc0[8], acc1[8];   // all indices compile-time after unroll
#pragma unroll
        for (int i = 0; i < 8; ++i) { acc0[i] = (v2f)0.f; acc1[i] = (v2f)0.f; }

#pragma unroll
        for (int lp = 0; lp < 8; ++lp) {
            const int l = sup * 8 + lp;
            const float scale = sc.s[l];
            level_point(tab, scale, px0, py0, pz0, acc0[lp]);
            level_point(tab, scale, px1, py1, pz1, acc1[lp]);

            if (lp == 7) {
                // one full 64-B line per point per super-phase
                size_t o0 = (size_t)(pbase + tid) * 8 + (size_t)sup * 4;
                out4[o0 + 0] = make_float4(acc0[0].x, acc0[0].y, acc0[1].x, acc0[1].y);
                out4[o0 + 1] = make_float4(acc0[2].x, acc0[2].y, acc0[3].x, acc0[3].y);
                out4[o0 + 2] = make_float4(acc0[4].x, acc0[4].y, acc0[5].x, acc0[5].y);
                out4[o0 + 3] = make_float4(acc0[6].x, acc0[6].y, acc0[7].x, acc0[7].y);
                size_t o1 = (size_t)(pbase + TPB + tid) * 8 + (size_t)sup * 4;
                out4[o1 + 0] = make_float4(acc1[0].x, acc1[0].y, acc1[1].x, acc1[1].y);
                out4[o1 + 1] = make_float4(acc1[2].x, acc1[2].y, acc1[3].x, acc1[3].y);
                out4[o1 + 2] = make_float4(acc1[4].x, acc1[4].y, acc1[5].x, acc1[5].y);
                out4[o1 + 3] = make_float4(acc1[6].x, acc1[6].y, acc1[7].x, acc1[7].y);
            }

            if (l < L_LEVELS - 1) {
                __syncthreads();          // all waves done gathering table l
                // reg -> LDS: table l+1 (compiler waits vmcnt on R)
#pragma unroll
                for (int k = 0; k < 8; ++k)
                    ((float4*)tab)[k * TPB + tid] = R[k];
                if (l < L_LEVELS - 2) {   // issue loads for table l+2
                    const float4* sn =
                        (const float4*)(tables + (size_t)(l + 2) * T_SIZE * 2);
#pragma unroll
                    for (int k = 0; k < 8; ++k) R[k] = sn[k * TPB + tid];
                }
                __syncthreads();          // table l+1 visible
            }
        }
    }
}

extern "C" void kernel_launch(void* const* d_in, const int* in_sizes, int n_in,
                              void* d_out, int out_size, void* d_ws, size_t ws_size,
                              hipStream_t stream) {
    const float* pts    = (const float*)d_in[0];
    const float* tables = (const float*)d_in[1];
    float* out = (float*)d_out;

    // numpy-exact: growth in f64, levels = float32(16 * g**l)
    Scales sc;
    double g = exp((log(512.0) - log(16.0)) / 15.0);
    for (int l = 0; l < L_LEVELS; ++l) sc.s[l] = (float)(16.0 * pow(g, (double)l));

    dim3 grid(NBLOCKS);    // 256 blocks, 1 per CU
    dim3 block(TPB);
    hipLaunchKernelGGL(mrhe_kernel, grid, block, 0, stream, pts, tables, out, sc);
}

// Round 6
// 251.706 us; speedup vs baseline: 2.2019x; 1.0863x over previous
//
#include <hip/hip_runtime.h>
#include <math.h>

#define L_LEVELS 16
#define T_SIZE   16384
#define BS_N     524288
#define TPB      1024
#define PPB      2048                 // points per block (2 per thread)
#define NBLOCKS  (BS_N / PPB)         // 256 = one block per CU

typedef float v2f __attribute__((ext_vector_type(2)));

struct Scales { float s[L_LEVELS]; };

// hash primes mod 2^14 (only low 14 bits of the int64 hash survive % T)
#define P2_14 ((unsigned)(2654435761u & (T_SIZE - 1)))
#define P3_14 ((unsigned)(805459861u  & (T_SIZE - 1)))
#define MASK3 ((T_SIZE - 1) << 3)     // byte-offset mask (8B entries)

__device__ __forceinline__ void level_point(const v2f* __restrict__ tab,
                                            float scale,
                                            float px, float py, float pz,
                                            v2f& acc)
{
    float sx = px * scale, sy = py * scale, sz = pz * scale;
    float fx = floorf(sx), fy = floorf(sy), fz = floorf(sz);
    float cx = ceilf(sx),  cy = ceilf(sy),  cz = ceilf(sz);

    unsigned ix0 = (unsigned)(int)fx, ix1 = (unsigned)(int)cx;
    unsigned iy0 = (unsigned)(int)fy, iy1 = (unsigned)(int)cy;
    unsigned iz0 = (unsigned)(int)fz, iz1 = (unsigned)(int)cz;
    unsigned hy0 = (iy0 & 0xFFFFFFu) * P2_14;
    unsigned hy1 = (iy1 & 0xFFFFFFu) * P2_14;
    unsigned hz0 = ((iz0 & 0xFFFFFFu) * P3_14) << 3;
    unsigned hz1 = ((iz1 & 0xFFFFFFu) * P3_14) << 3;
    unsigned a00 = (ix0 ^ hy0) << 3, a01 = (ix0 ^ hy1) << 3;
    unsigned a10 = (ix1 ^ hy0) << 3, a11 = (ix1 ^ hy1) << 3;

    v2f ex = (v2f){fx, cx} - px;
    v2f ey = (v2f){fy, cy} - py;
    v2f ez = (v2f){fz, cz} - pz;
    v2f qx = ex * ex, qy = ey * ey, qz = ez * ez;
    v2f AB0 = qx + qy.xx, AB1 = qx + qy.yy;
    v2f S00 = AB0 + qz.xx, S01 = AB0 + qz.yy;
    v2f S10 = AB1 + qz.xx, S11 = AB1 + qz.yy;

    // raw v_sqrt_f32 (1 ulp) -- error * max-dist ~1e-4, threshold is 0.1
    float d0 = __builtin_amdgcn_sqrtf(S00.x), d1 = __builtin_amdgcn_sqrtf(S01.x);
    float d2 = __builtin_amdgcn_sqrtf(S10.x), d3 = __builtin_amdgcn_sqrtf(S11.x);
    float d4 = __builtin_amdgcn_sqrtf(S00.y), d5 = __builtin_amdgcn_sqrtf(S01.y);
    float d6 = __builtin_amdgcn_sqrtf(S10.y), d7 = __builtin_amdgcn_sqrtf(S11.y);

    const char* tb = (const char*)tab;
    v2f f0 = *(const v2f*)(tb + ((a00 ^ hz0) & MASK3));
    v2f f1 = *(const v2f*)(tb + ((a00 ^ hz1) & MASK3));
    v2f f2 = *(const v2f*)(tb + ((a01 ^ hz0) & MASK3));
    v2f f3 = *(const v2f*)(tb + ((a01 ^ hz1) & MASK3));
    v2f f4 = *(const v2f*)(tb + ((a10 ^ hz0) & MASK3));
    v2f f5 = *(const v2f*)(tb + ((a10 ^ hz1) & MASK3));
    v2f f6 = *(const v2f*)(tb + ((a11 ^ hz0) & MASK3));
    v2f f7 = *(const v2f*)(tb + ((a11 ^ hz1) & MASK3));

    acc += f0 * d0;  acc += f1 * d1;  acc += f2 * d2;  acc += f3 * d3;
    acc += f4 * d4;  acc += f5 * d5;  acc += f6 * d6;  acc += f7 * d7;
}

// Point-major fused kernel. amdgpu_waves_per_eu(4,4) pins the compiler to
// the occupancy the 128-KB LDS forces anyway (1 block/CU = 4 waves/EU),
// raising the VGPR budget to 128 so acc[16]+R[8] stay in registers
// (round-5 counters showed R[8] spilling to scratch under a 64-VGPR cap:
// WRITE_SIZE excess 493 MB == 15 stagings x 128 B x 262144 threads).
__global__ __launch_bounds__(TPB)
__attribute__((amdgpu_waves_per_eu(4, 4)))
void mrhe_kernel(
    const float* __restrict__ pts,
    const float* __restrict__ tables,
    float* __restrict__ out,
    Scales sc)
{
    __shared__ __align__(16) v2f tab[T_SIZE];   // 128 KB current level table

    const unsigned tid   = threadIdx.x;
    const unsigned pbase = blockIdx.x * PPB;

    const float* pp0 = pts + (size_t)(pbase + tid) * 3;
    const float* pp1 = pts + (size_t)(pbase + TPB + tid) * 3;
    float px0 = pp0[0], py0 = pp0[1], pz0 = pp0[2];
    float px1 = pp1[0], py1 = pp1[1], pz1 = pp1[2];

    // ---- prologue: table 0 direct-to-LDS; reg loads for table 1 ----
    {
        const char* gsrc = (const char*)tables;
        char* lbase = (char*)tab;
#pragma unroll
        for (int k = 0; k < 8; ++k) {
            unsigned off = (k * TPB + tid) * 16u;
            __builtin_amdgcn_global_load_lds(
                (const __attribute__((address_space(1))) unsigned int*)(gsrc + off),
                (__attribute__((address_space(3))) unsigned int*)(lbase + off),
                16, 0, 0);
        }
    }
    float4 R[8];   // T14 staging regs for the NEXT level's table
    {
        const float4* s1 = (const float4*)(tables + (size_t)T_SIZE * 2);
#pragma unroll
        for (int k = 0; k < 8; ++k) R[k] = s1[k * TPB + tid];
    }
    __syncthreads();   // vmcnt drained: table 0 resident

    float4* __restrict__ out4 = (float4*)out;

#pragma unroll
    for (int sup = 0; sup < 2; ++sup) {
        v2f acc0[8], acc1[8];   // all indices compile-time after unroll
#pragma unroll
        for (int i = 0; i < 8; ++i) { acc0[i] = (v2f)0.f; acc1[i] = (v2f)0.f; }

#pragma unroll
        for (int lp = 0; lp < 8; ++lp) {
            const int l = sup * 8 + lp;
            const float scale = sc.s[l];
            level_point(tab, scale, px0, py0, pz0, acc0[lp]);
            level_point(tab, scale, px1, py1, pz1, acc1[lp]);

            if (lp == 7) {
                // one full 64-B line per point per super-phase
                size_t o0 = (size_t)(pbase + tid) * 8 + (size_t)sup * 4;
                out4[o0 + 0] = make_float4(acc0[0].x, acc0[0].y, acc0[1].x, acc0[1].y);
                out4[o0 + 1] = make_float4(acc0[2].x, acc0[2].y, acc0[3].x, acc0[3].y);
                out4[o0 + 2] = make_float4(acc0[4].x, acc0[4].y, acc0[5].x, acc0[5].y);
                out4[o0 + 3] = make_float4(acc0[6].x, acc0[6].y, acc0[7].x, acc0[7].y);
                size_t o1 = (size_t)(pbase + TPB + tid) * 8 + (size_t)sup * 4;
                out4[o1 + 0] = make_float4(acc1[0].x, acc1[0].y, acc1[1].x, acc1[1].y);
                out4[o1 + 1] = make_float4(acc1[2].x, acc1[2].y, acc1[3].x, acc1[3].y);
                out4[o1 + 2] = make_float4(acc1[4].x, acc1[4].y, acc1[5].x, acc1[5].y);
                out4[o1 + 3] = make_float4(acc1[6].x, acc1[6].y, acc1[7].x, acc1[7].y);
            }

            if (l < L_LEVELS - 1) {
                __syncthreads();          // all waves done gathering table l
                // reg -> LDS: table l+1 (compiler waits vmcnt on R)
#pragma unroll
                for (int k = 0; k < 8; ++k)
                    ((float4*)tab)[k * TPB + tid] = R[k];
                if (l < L_LEVELS - 2) {   // issue loads for table l+2
                    const float4* sn =
                        (const float4*)(tables + (size_t)(l + 2) * T_SIZE * 2);
#pragma unroll
                    for (int k = 0; k < 8; ++k) R[k] = sn[k * TPB + tid];
                }
                __syncthreads();          // table l+1 visible
            }
        }
    }
}

extern "C" void kernel_launch(void* const* d_in, const int* in_sizes, int n_in,
                              void* d_out, int out_size, void* d_ws, size_t ws_size,
                              hipStream_t stream) {
    const float* pts    = (const float*)d_in[0];
    const float* tables = (const float*)d_in[1];
    float* out = (float*)d_out;

    // numpy-exact: growth in f64, levels = float32(16 * g**l)
    Scales sc;
    double g = exp((log(512.0) - log(16.0)) / 15.0);
    for (int l = 0; l < L_LEVELS; ++l) sc.s[l] = (float)(16.0 * pow(g, (double)l));

    dim3 grid(NBLOCKS);    // 256 blocks, 1 per CU
    dim3 block(TPB);
    hipLaunchKernelGGL(mrhe_kernel, grid, block, 0, stream, pts, tables, out, sc);
}

// Round 8
// 213.063 us; speedup vs baseline: 2.6013x; 1.1814x over previous
//
#include <hip/hip_runtime.h>
#include <math.h>

#define L_LEVELS 16
#define T_SIZE   16384
#define BS_N     524288
#define TPB      1024
#define PPB      2048                 // points per block (2 per thread)
#define NBLOCKS  (BS_N / PPB)         // 256 = one block per CU

typedef float v2f __attribute__((ext_vector_type(2)));
typedef float v4f __attribute__((ext_vector_type(4)));   // clang vector: OK for nontemporal builtin

struct Scales { float s[L_LEVELS]; };

// hash primes mod 2^14 (only low 14 bits of the int64 hash survive % T)
#define P2_14 ((unsigned)(2654435761u & (T_SIZE - 1)))
#define P3_14 ((unsigned)(805459861u  & (T_SIZE - 1)))
#define MASK3 ((T_SIZE - 1) << 3)     // byte-offset mask (8B entries)

__device__ __forceinline__ void level_point(const v2f* __restrict__ tab,
                                            float scale,
                                            float px, float py, float pz,
                                            v2f& acc)
{
    float sx = px * scale, sy = py * scale, sz = pz * scale;
    float fx = floorf(sx), fy = floorf(sy), fz = floorf(sz);
    float cx = ceilf(sx),  cy = ceilf(sy),  cz = ceilf(sz);

    unsigned ix0 = (unsigned)(int)fx, ix1 = (unsigned)(int)cx;
    unsigned iy0 = (unsigned)(int)fy, iy1 = (unsigned)(int)cy;
    unsigned iz0 = (unsigned)(int)fz, iz1 = (unsigned)(int)cz;
    unsigned hy0 = (iy0 & 0xFFFFFFu) * P2_14;
    unsigned hy1 = (iy1 & 0xFFFFFFu) * P2_14;
    unsigned hz0 = ((iz0 & 0xFFFFFFu) * P3_14) << 3;
    unsigned hz1 = ((iz1 & 0xFFFFFFu) * P3_14) << 3;
    unsigned a00 = (ix0 ^ hy0) << 3, a01 = (ix0 ^ hy1) << 3;
    unsigned a10 = (ix1 ^ hy0) << 3, a11 = (ix1 ^ hy1) << 3;

    v2f ex = (v2f){fx, cx} - px;
    v2f ey = (v2f){fy, cy} - py;
    v2f ez = (v2f){fz, cz} - pz;
    v2f qx = ex * ex, qy = ey * ey, qz = ez * ez;
    v2f AB0 = qx + qy.xx, AB1 = qx + qy.yy;
    v2f S00 = AB0 + qz.xx, S01 = AB0 + qz.yy;
    v2f S10 = AB1 + qz.xx, S11 = AB1 + qz.yy;

    // raw v_sqrt_f32 (1 ulp) -- error * max-dist ~1e-4, threshold is 0.1
    float d0 = __builtin_amdgcn_sqrtf(S00.x), d1 = __builtin_amdgcn_sqrtf(S01.x);
    float d2 = __builtin_amdgcn_sqrtf(S10.x), d3 = __builtin_amdgcn_sqrtf(S11.x);
    float d4 = __builtin_amdgcn_sqrtf(S00.y), d5 = __builtin_amdgcn_sqrtf(S01.y);
    float d6 = __builtin_amdgcn_sqrtf(S10.y), d7 = __builtin_amdgcn_sqrtf(S11.y);

    const char* tb = (const char*)tab;
    v2f f0 = *(const v2f*)(tb + ((a00 ^ hz0) & MASK3));
    v2f f1 = *(const v2f*)(tb + ((a00 ^ hz1) & MASK3));
    v2f f2 = *(const v2f*)(tb + ((a01 ^ hz0) & MASK3));
    v2f f3 = *(const v2f*)(tb + ((a01 ^ hz1) & MASK3));
    v2f f4 = *(const v2f*)(tb + ((a10 ^ hz0) & MASK3));
    v2f f5 = *(const v2f*)(tb + ((a10 ^ hz1) & MASK3));
    v2f f6 = *(const v2f*)(tb + ((a11 ^ hz0) & MASK3));
    v2f f7 = *(const v2f*)(tb + ((a11 ^ hz1) & MASK3));

    acc += f0 * d0;  acc += f1 * d1;  acc += f2 * d2;  acc += f3 * d3;
    acc += f4 * d4;  acc += f5 * d5;  acc += f6 * d6;  acc += f7 * d7;
}

// Point-major fused kernel, zero-staging-VGPR edition.
// Rounds 5/6 proved the compiler pins 1024-thread blocks at 64 VGPRs
// (both occupancy hints ignored; WRITE_SIZE excess == R[8] spill traffic to
// 0.08%). So: stage each level's table with global_load_lds (no VGPRs),
// keep live state (acc 32 + pts 6 + temps ~22) under the 64 cap.
// Output: each thread fully writes its own 64-B line; nontemporal stores
// keep the 64 MB output stream from evicting the L2-resident tables.
__global__ __launch_bounds__(TPB) void mrhe_kernel(
    const float* __restrict__ pts,
    const float* __restrict__ tables,
    float* __restrict__ out,
    Scales sc)
{
    __shared__ __align__(16) v2f tab[T_SIZE];   // 128 KB current level table

    const unsigned tid   = threadIdx.x;
    const unsigned pbase = blockIdx.x * PPB;

    const float* pp0 = pts + (size_t)(pbase + tid) * 3;
    const float* pp1 = pts + (size_t)(pbase + TPB + tid) * 3;
    float px0 = pp0[0], py0 = pp0[1], pz0 = pp0[2];
    float px1 = pp1[0], py1 = pp1[1], pz1 = pp1[2];

    // ---- prologue: table 0 direct-to-LDS ----
    {
        const char* gsrc = (const char*)tables;
        char* lbase = (char*)tab;
#pragma unroll
        for (int k = 0; k < 8; ++k) {
            unsigned off = (k * TPB + tid) * 16u;
            __builtin_amdgcn_global_load_lds(
                (const __attribute__((address_space(1))) unsigned int*)(gsrc + off),
                (__attribute__((address_space(3))) unsigned int*)(lbase + off),
                16, 0, 0);
        }
    }
    __syncthreads();   // vmcnt drained: table 0 resident

    v4f* __restrict__ out4 = (v4f*)out;

#pragma unroll
    for (int sup = 0; sup < 2; ++sup) {
        v2f acc0[8], acc1[8];   // all indices compile-time after unroll
#pragma unroll
        for (int i = 0; i < 8; ++i) { acc0[i] = (v2f)0.f; acc1[i] = (v2f)0.f; }

#pragma unroll
        for (int lp = 0; lp < 8; ++lp) {
            const int l = sup * 8 + lp;
            const float scale = sc.s[l];
            level_point(tab, scale, px0, py0, pz0, acc0[lp]);
            level_point(tab, scale, px1, py1, pz1, acc1[lp]);

            if (l < L_LEVELS - 1) {
                __syncthreads();   // all gathers of table l complete
                // stage table l+1 direct-to-LDS (no VGPR cost)
                const char* gsrc = (const char*)(tables
                                   + (size_t)(l + 1) * (T_SIZE * 2));
                char* lbase = (char*)tab;
#pragma unroll
                for (int k = 0; k < 8; ++k) {
                    unsigned off = (k * TPB + tid) * 16u;
                    __builtin_amdgcn_global_load_lds(
                        (const __attribute__((address_space(1))) unsigned int*)(gsrc + off),
                        (__attribute__((address_space(3))) unsigned int*)(lbase + off),
                        16, 0, 0);
                }
            }

            if (lp == 7) {
                // one full 64-B line per point per super-phase, streamed NT
                // (issued between staging-issue and drain barrier -> overlap)
                size_t o0 = (size_t)(pbase + tid) * 8 + (size_t)sup * 4;
                __builtin_nontemporal_store(
                    (v4f){acc0[0].x, acc0[0].y, acc0[1].x, acc0[1].y}, &out4[o0 + 0]);
                __builtin_nontemporal_store(
                    (v4f){acc0[2].x, acc0[2].y, acc0[3].x, acc0[3].y}, &out4[o0 + 1]);
                __builtin_nontemporal_store(
                    (v4f){acc0[4].x, acc0[4].y, acc0[5].x, acc0[5].y}, &out4[o0 + 2]);
                __builtin_nontemporal_store(
                    (v4f){acc0[6].x, acc0[6].y, acc0[7].x, acc0[7].y}, &out4[o0 + 3]);
                size_t o1 = (size_t)(pbase + TPB + tid) * 8 + (size_t)sup * 4;
                __builtin_nontemporal_store(
                    (v4f){acc1[0].x, acc1[0].y, acc1[1].x, acc1[1].y}, &out4[o1 + 0]);
                __builtin_nontemporal_store(
                    (v4f){acc1[2].x, acc1[2].y, acc1[3].x, acc1[3].y}, &out4[o1 + 1]);
                __builtin_nontemporal_store(
                    (v4f){acc1[4].x, acc1[4].y, acc1[5].x, acc1[5].y}, &out4[o1 + 2]);
                __builtin_nontemporal_store(
                    (v4f){acc1[6].x, acc1[6].y, acc1[7].x, acc1[7].y}, &out4[o1 + 3]);
            }

            if (l < L_LEVELS - 1)
                __syncthreads();   // vmcnt(0) drain: table l+1 resident
        }
    }
}

extern "C" void kernel_launch(void* const* d_in, const int* in_sizes, int n_in,
                              void* d_out, int out_size, void* d_ws, size_t ws_size,
                              hipStream_t stream) {
    const float* pts    = (const float*)d_in[0];
    const float* tables = (const float*)d_in[1];
    float* out = (float*)d_out;

    // numpy-exact: growth in f64, levels = float32(16 * g**l)
    Scales sc;
    double g = exp((log(512.0) - log(16.0)) / 15.0);
    for (int l = 0; l < L_LEVELS; ++l) sc.s[l] = (float)(16.0 * pow(g, (double)l));

    dim3 grid(NBLOCKS);    // 256 blocks, 1 per CU
    dim3 block(TPB);
    hipLaunchKernelGGL(mrhe_kernel, grid, block, 0, stream, pts, tables, out, sc);
}